// Round 2
// baseline (1207.476 us; speedup 1.0000x reference)
//
#include <hip/hip_runtime.h>
#include <hip/hip_bf16.h>

typedef unsigned short ushort_t;
typedef __attribute__((ext_vector_type(8))) short short8;
typedef __attribute__((ext_vector_type(4))) float f32x4;

#define HIDDEN 256
#define N_NODES 50000
#define BM 64
#define LDSROW 528  // 256 bf16 = 512B, +16B pad -> bank-conflict-free ds_read_b128
#define MV_BYTES ((size_t)N_NODES * HIDDEN * sizeof(float))

__device__ __forceinline__ unsigned int f2bf(float f) {
    union { float f; unsigned int i; } v; v.f = f;
    return (v.i + 0x7fffu + ((v.i >> 16) & 1u)) >> 16;
}

// Kernel 0: W fp32 -> bf16 (once per launch; 65536 elements, trivial)
__global__ void convert_w(const float* __restrict__ W, ushort_t* __restrict__ Wb, int n) {
    int i = blockIdx.x * blockDim.x + threadIdx.x;
    if (i < n) Wb[i] = (ushort_t)f2bf(W[i]);
}

// Kernel 1: M_v[dst[e]] += relu(E[e])  (fp32 atomics, skip non-positive)
__global__ void scatter_relu_sum(const float4* __restrict__ E4,
                                 const int* __restrict__ dst,
                                 float* __restrict__ Mv, int n_chunks) {
    int idx = blockIdx.x * blockDim.x + threadIdx.x;
    if (idx >= n_chunks) return;
    int e = idx >> 6;          // 64 chunks of 4 floats per edge row
    int c = idx & 63;
    float4 v = E4[idx];
    int d = dst[e];
    float* p = Mv + (size_t)d * HIDDEN + c * 4;
    if (v.x > 0.0f) atomicAdd(p + 0, v.x);
    if (v.y > 0.0f) atomicAdd(p + 1, v.y);
    if (v.z > 0.0f) atomicAdd(p + 2, v.z);
    if (v.w > 0.0f) atomicAdd(p + 3, v.w);
}

// Kernel 2: out = (Mv[src] - relu(E[rev])) @ W.T + b   (bf16 MFMA, fp32 out)
__global__ __launch_bounds__(256, 4)
void gemm_update(const float* __restrict__ E,
                 const int* __restrict__ src,
                 const int* __restrict__ rev,
                 const float* __restrict__ Mv,
                 const ushort_t* __restrict__ Wb,
                 const float* __restrict__ bias,
                 float* __restrict__ out, int n_edges) {
    __shared__ __align__(16) unsigned char lds[BM * LDSROW];
    const int tid = threadIdx.x;
    const int row0 = blockIdx.x * BM;

    // ---- stage A tile: A[r][k] = Mv[src[r]][k] - relu(E[rev[r]][k]), as bf16
    {
        const int r = tid >> 2;        // 64 rows, 4 threads/row
        const int q = tid & 3;         // each thread covers 64 k
        const int gr = row0 + r;
        uint2* ldst = (uint2*)(lds + r * LDSROW + q * 128);
        if (gr < n_edges) {
            const int s  = src[gr];
            const int rv = rev[gr];
            const float4* mvp = (const float4*)(Mv + (size_t)s  * HIDDEN + q * 64);
            const float4* ep  = (const float4*)(E  + (size_t)rv * HIDDEN + q * 64);
#pragma unroll
            for (int c = 0; c < 16; ++c) {
                float4 ev = ep[c];
                float4 mv = mvp[c];
                float v0 = mv.x - fmaxf(ev.x, 0.0f);
                float v1 = mv.y - fmaxf(ev.y, 0.0f);
                float v2 = mv.z - fmaxf(ev.z, 0.0f);
                float v3 = mv.w - fmaxf(ev.w, 0.0f);
                uint2 o;
                o.x = f2bf(v0) | (f2bf(v1) << 16);
                o.y = f2bf(v2) | (f2bf(v3) << 16);
                ldst[c] = o;
            }
        } else {
            uint2 z = {0, 0};
#pragma unroll
            for (int c = 0; c < 16; ++c) ldst[c] = z;
        }
    }
    __syncthreads();

    // ---- MFMA: each wave owns 64 rows x 64 cols
    const int lane  = tid & 63;
    const int wid   = tid >> 6;
    const int l15   = lane & 15;
    const int hi16  = lane >> 4;
    const int wcol0 = wid * 64;

    f32x4 acc[4][4];
#pragma unroll
    for (int m = 0; m < 4; ++m)
#pragma unroll
        for (int n = 0; n < 4; ++n)
            acc[m][n] = (f32x4){0.f, 0.f, 0.f, 0.f};

#pragma unroll 1
    for (int kk = 0; kk < 8; ++kk) {
        short8 a[4], bfr[4];
#pragma unroll
        for (int m = 0; m < 4; ++m) {
            const int row = m * 16 + l15;
            a[m] = *(const short8*)(lds + row * LDSROW + kk * 64 + hi16 * 16);
        }
#pragma unroll
        for (int n = 0; n < 4; ++n) {
            const int j = wcol0 + n * 16 + l15;   // out col -> W row (out = A @ W.T)
            bfr[n] = *(const short8*)(Wb + (size_t)j * HIDDEN + kk * 32 + hi16 * 8);
        }
#pragma unroll
        for (int m = 0; m < 4; ++m)
#pragma unroll
            for (int n = 0; n < 4; ++n)
                acc[m][n] = __builtin_amdgcn_mfma_f32_16x16x32_bf16(a[m], bfr[n], acc[m][n], 0, 0, 0);
    }

    // ---- epilogue: +bias, store fp32. C/D: col=lane&15, row=(lane>>4)*4+reg
#pragma unroll
    for (int n = 0; n < 4; ++n) {
        const int col = wcol0 + n * 16 + l15;
        const float bv = bias[col];
#pragma unroll
        for (int m = 0; m < 4; ++m) {
            const int rbase = row0 + m * 16 + hi16 * 4;
#pragma unroll
            for (int j = 0; j < 4; ++j) {
                const int row = rbase + j;
                if (row < n_edges)
                    out[(size_t)row * HIDDEN + col] = acc[m][n][j] + bv;
            }
        }
    }
}

extern "C" void kernel_launch(void* const* d_in, const int* in_sizes, int n_in,
                              void* d_out, int out_size, void* d_ws, size_t ws_size,
                              hipStream_t stream) {
    const float* E    = (const float*)d_in[0];
    const int*   ei   = (const int*)d_in[1];
    const int*   rev  = (const int*)d_in[2];
    const float* W    = (const float*)d_in[3];
    const float* bias = (const float*)d_in[4];
    float* out = (float*)d_out;
    const int n_edges = in_sizes[2];
    const int* srcI = ei;              // edge_index[0]
    const int* dstI = ei + n_edges;    // edge_index[1]

    float*    Mv = (float*)d_ws;
    ushort_t* Wb = (ushort_t*)((char*)d_ws + MV_BYTES);

    hipMemsetAsync(d_ws, 0, MV_BYTES, stream);

    convert_w<<<(HIDDEN * HIDDEN + 255) / 256, 256, 0, stream>>>(W, Wb, HIDDEN * HIDDEN);

    const int n_chunks = n_edges * (HIDDEN / 4);
    scatter_relu_sum<<<(n_chunks + 255) / 256, 256, 0, stream>>>(
        (const float4*)E, dstI, Mv, n_chunks);

    const int nblk = (n_edges + BM - 1) / BM;
    gemm_update<<<nblk, 256, 0, stream>>>(E, srcI, rev, Mv, Wb, bias, out, n_edges);
}

// Round 3
// 502.006 us; speedup vs baseline: 2.4053x; 2.4053x over previous
//
#include <hip/hip_runtime.h>
#include <hip/hip_bf16.h>

typedef unsigned short ushort_t;
typedef __attribute__((ext_vector_type(8))) short short8;
typedef __attribute__((ext_vector_type(4))) float f32x4;

#define HIDDEN 256
#define N_NODES 50000
#define BM 64
#define LDSROW 528  // 64 cols/thread * 4 stage-threads = 512B + 16B pad

__device__ __forceinline__ unsigned int f2bf(float f) {
    union { float f; unsigned int i; } v; v.f = f;
    return (v.i + 0x7fffu + ((v.i >> 16) & 1u)) >> 16;
}
__device__ __forceinline__ float bf2f(unsigned int u) {
    union { unsigned int i; float f; } v; v.i = u << 16; return v.f;
}

// ws layout (bytes)
#define OFF_MVB    0u                         // 50000*256 bf16 = 25,600,000
#define OFF_WB     25600000u                  // 65536 bf16     =    131,072
#define OFF_CNT    25731072u                  // int[50000]     =    200,000
#define OFF_OFFS   25931072u                  // int[50001]     =    200,004
#define OFF_CUR    26131076u                  // int[50000]     =    200,000
#define OFF_ELIST  26331076u                  // int[300000]    =  1,200,000

// Kernel 0: W fp32 -> bf16
__global__ void convert_w(const float* __restrict__ W, ushort_t* __restrict__ Wb, int n) {
    int i = blockIdx.x * blockDim.x + threadIdx.x;
    if (i < n) Wb[i] = (ushort_t)f2bf(W[i]);
}

// Kernel 1: histogram of dst
__global__ void count_dst(const int* __restrict__ dst, int* __restrict__ cnt, int n) {
    int i = blockIdx.x * blockDim.x + threadIdx.x;
    if (i < n) atomicAdd(&cnt[dst[i]], 1);
}

// Kernel 2: single-block exclusive scan over counts -> offsets, cursor
__global__ __launch_bounds__(1024)
void scan_counts(const int* __restrict__ cnt, int* __restrict__ offs,
                 int* __restrict__ cur) {
    __shared__ int part[1024];
    const int t = threadIdx.x;
    const int chunk = (N_NODES + 1023) / 1024;
    const int base = t * chunk;
    int s = 0;
    for (int i = 0; i < chunk; ++i) {
        int idx = base + i;
        if (idx < N_NODES) s += cnt[idx];
    }
    part[t] = s;
    __syncthreads();
    // inclusive scan (Hillis-Steele)
    for (int off = 1; off < 1024; off <<= 1) {
        int v = (t >= off) ? part[t - off] : 0;
        __syncthreads();
        part[t] += v;
        __syncthreads();
    }
    int run = (t == 0) ? 0 : part[t - 1];
    for (int i = 0; i < chunk; ++i) {
        int idx = base + i;
        if (idx < N_NODES) {
            offs[idx] = run;
            cur[idx] = run;
            run += cnt[idx];
        }
    }
    if (t == 1023) offs[N_NODES] = part[1023];
}

// Kernel 3: bucket edge ids by destination
__global__ void fill_elist(const int* __restrict__ dst, int* __restrict__ cur,
                           int* __restrict__ elist, int n) {
    int i = blockIdx.x * blockDim.x + threadIdx.x;
    if (i < n) {
        int d = dst[i];
        int pos = atomicAdd(&cur[d], 1);
        elist[pos] = i;
    }
}

// Kernel 4: per-node register-accumulated relu-sum -> Mv (bf16)
__global__ __launch_bounds__(256)
void node_gather_sum(const float* __restrict__ E,
                     const int* __restrict__ offs,
                     const int* __restrict__ elist,
                     unsigned int* __restrict__ Mvb) {
    const int node = blockIdx.x * 4 + (threadIdx.x >> 6);
    const int lane = threadIdx.x & 63;
    if (node >= N_NODES) return;
    const int s0 = offs[node];
    const int s1 = offs[node + 1];
    float4 acc = {0.f, 0.f, 0.f, 0.f};
    for (int j = s0; j < s1; ++j) {
        const int e = elist[j];
        float4 v = *(const float4*)(E + (size_t)e * HIDDEN + lane * 4);
        acc.x += fmaxf(v.x, 0.f);
        acc.y += fmaxf(v.y, 0.f);
        acc.z += fmaxf(v.z, 0.f);
        acc.w += fmaxf(v.w, 0.f);
    }
    uint2 o;
    o.x = f2bf(acc.x) | (f2bf(acc.y) << 16);
    o.y = f2bf(acc.z) | (f2bf(acc.w) << 16);
    *(uint2*)(Mvb + (size_t)node * (HIDDEN / 2) + lane * 2) = o;
}

// Kernel 5: out = (Mv[src] - relu(E[rev])) @ W.T + b   (bf16 MFMA, fp32 out)
__global__ __launch_bounds__(256, 4)
void gemm_update(const float* __restrict__ E,
                 const int* __restrict__ src,
                 const int* __restrict__ rev,
                 const unsigned int* __restrict__ Mvb,
                 const ushort_t* __restrict__ Wb,
                 const float* __restrict__ bias,
                 float* __restrict__ out, int n_edges) {
    __shared__ __align__(16) unsigned char lds[BM * LDSROW];
    const int tid = threadIdx.x;
    const int row0 = blockIdx.x * BM;

    // ---- stage A tile: A[r][k] = Mv[src[r]][k] - relu(E[rev[r]][k]), as bf16
    {
        const int r = tid >> 2;        // 64 rows, 4 threads/row
        const int q = tid & 3;         // each thread covers 64 cols
        const int gr = row0 + r;
        uint2* ldst = (uint2*)(lds + r * LDSROW + q * 128);
        if (gr < n_edges) {
            const int s  = src[gr];
            const int rv = rev[gr];
            const uint2*  mvp = (const uint2*)(Mvb + (size_t)s * (HIDDEN / 2)) + q * 16;
            const float4* ep  = (const float4*)(E + (size_t)rv * HIDDEN + q * 64);
#pragma unroll
            for (int c = 0; c < 16; ++c) {
                float4 ev = ep[c];
                uint2  mv = mvp[c];
                float v0 = bf2f(mv.x & 0xffffu) - fmaxf(ev.x, 0.f);
                float v1 = bf2f(mv.x >> 16)     - fmaxf(ev.y, 0.f);
                float v2 = bf2f(mv.y & 0xffffu) - fmaxf(ev.z, 0.f);
                float v3 = bf2f(mv.y >> 16)     - fmaxf(ev.w, 0.f);
                uint2 o;
                o.x = f2bf(v0) | (f2bf(v1) << 16);
                o.y = f2bf(v2) | (f2bf(v3) << 16);
                ldst[c] = o;
            }
        } else {
            uint2 z = {0, 0};
#pragma unroll
            for (int c = 0; c < 16; ++c) ldst[c] = z;
        }
    }
    __syncthreads();

    // ---- MFMA: each wave owns 64 rows x 64 cols
    const int lane  = tid & 63;
    const int wid   = tid >> 6;
    const int l15   = lane & 15;
    const int hi16  = lane >> 4;
    const int wcol0 = wid * 64;

    f32x4 acc[4][4];
#pragma unroll
    for (int m = 0; m < 4; ++m)
#pragma unroll
        for (int n = 0; n < 4; ++n)
            acc[m][n] = (f32x4){0.f, 0.f, 0.f, 0.f};

#pragma unroll 1
    for (int kk = 0; kk < 8; ++kk) {
        short8 a[4], bfr[4];
#pragma unroll
        for (int m = 0; m < 4; ++m) {
            const int row = m * 16 + l15;
            a[m] = *(const short8*)(lds + row * LDSROW + kk * 64 + hi16 * 16);
        }
#pragma unroll
        for (int n = 0; n < 4; ++n) {
            const int j = wcol0 + n * 16 + l15;   // out col -> W row (out = A @ W.T)
            bfr[n] = *(const short8*)(Wb + (size_t)j * HIDDEN + kk * 32 + hi16 * 8);
        }
#pragma unroll
        for (int m = 0; m < 4; ++m)
#pragma unroll
            for (int n = 0; n < 4; ++n)
                acc[m][n] = __builtin_amdgcn_mfma_f32_16x16x32_bf16(a[m], bfr[n], acc[m][n], 0, 0, 0);
    }

    // ---- epilogue: +bias, store fp32. C/D: col=lane&15, row=(lane>>4)*4+reg
#pragma unroll
    for (int n = 0; n < 4; ++n) {
        const int col = wcol0 + n * 16 + l15;
        const float bv = bias[col];
#pragma unroll
        for (int m = 0; m < 4; ++m) {
            const int rbase = row0 + m * 16 + hi16 * 4;
#pragma unroll
            for (int j = 0; j < 4; ++j) {
                const int row = rbase + j;
                if (row < n_edges)
                    out[(size_t)row * HIDDEN + col] = acc[m][n][j] + bv;
            }
        }
    }
}

extern "C" void kernel_launch(void* const* d_in, const int* in_sizes, int n_in,
                              void* d_out, int out_size, void* d_ws, size_t ws_size,
                              hipStream_t stream) {
    const float* E    = (const float*)d_in[0];
    const int*   ei   = (const int*)d_in[1];
    const int*   rev  = (const int*)d_in[2];
    const float* W    = (const float*)d_in[3];
    const float* bias = (const float*)d_in[4];
    float* out = (float*)d_out;
    const int n_edges = in_sizes[2];
    const int* srcI = ei;              // edge_index[0]
    const int* dstI = ei + n_edges;    // edge_index[1]

    char* ws = (char*)d_ws;
    unsigned int* Mvb  = (unsigned int*)(ws + OFF_MVB);
    ushort_t*     Wb   = (ushort_t*)(ws + OFF_WB);
    int*          cnt  = (int*)(ws + OFF_CNT);
    int*          offs = (int*)(ws + OFF_OFFS);
    int*          cur  = (int*)(ws + OFF_CUR);
    int*          elst = (int*)(ws + OFF_ELIST);

    hipMemsetAsync(cnt, 0, N_NODES * sizeof(int), stream);

    convert_w<<<(HIDDEN * HIDDEN + 255) / 256, 256, 0, stream>>>(W, Wb, HIDDEN * HIDDEN);

    count_dst<<<(n_edges + 255) / 256, 256, 0, stream>>>(dstI, cnt, n_edges);
    scan_counts<<<1, 1024, 0, stream>>>(cnt, offs, cur);
    fill_elist<<<(n_edges + 255) / 256, 256, 0, stream>>>(dstI, cur, elst, n_edges);

    node_gather_sum<<<(N_NODES + 3) / 4, 256, 0, stream>>>(E, offs, elst, Mvb);

    const int nblk = (n_edges + BM - 1) / BM;
    gemm_update<<<nblk, 256, 0, stream>>>(E, srcI, rev, Mvb, Wb, bias, out, n_edges);
}